// Round 1
// baseline (2107.740 us; speedup 1.0000x reference)
//
#include <hip/hip_runtime.h>
#include <math.h>

#define B_  2
#define T_  2048
#define C_  1024
#define H_  16
#define HD_ 64
#define FC_ 5120   // 5*C

// ---------------- RMSNorm: xn = x / max(||x||*C^-0.5, 1e-8) * rms_w ----------------
__global__ __launch_bounds__(256) void rmsnorm_kernel(const float* __restrict__ x,
                                                      const float* __restrict__ rms_w,
                                                      float* __restrict__ xn) {
    int row = blockIdx.x;                       // 0..4095
    int tid = threadIdx.x;                      // 256 threads, 4 floats each
    float4 v = ((const float4*)(x + (size_t)row * C_))[tid];
    float ss = v.x*v.x + v.y*v.y + v.z*v.z + v.w*v.w;
    #pragma unroll
    for (int m = 32; m >= 1; m >>= 1) ss += __shfl_xor(ss, m);
    __shared__ float wsum[4];
    if ((tid & 63) == 0) wsum[tid >> 6] = ss;
    __syncthreads();
    float tot = wsum[0] + wsum[1] + wsum[2] + wsum[3];
    float nrm = sqrtf(tot) * 0.03125f;          // * C^-0.5 (C=1024)
    float inv = 1.0f / fmaxf(nrm, 1e-8f);
    float4 w = ((const float4*)rms_w)[tid];
    float4 o;
    o.x = v.x * inv * w.x;  o.y = v.y * inv * w.y;
    o.z = v.z * inv * w.z;  o.w = v.w * inv * w.w;
    ((float4*)(xn + (size_t)row * C_))[tid] = o;
}

// ---------------- xpos rotary on q and k (in-place in qkvff) ----------------
__global__ __launch_bounds__(256) void xpos_kernel(float* __restrict__ qkvff) {
    int bt = blockIdx.x;
    int t = bt & (T_ - 1);
    float* row = qkvff + (size_t)bt * FC_;
    float power = (float)(t - T_/2) * (1.0f / 512.0f);   // (t - 1024)/SCALE_BASE
    for (int i = threadIdx.x; i < 512; i += 256) {       // pair index, half=512
        float sv    = (2.0f * (float)i + 409.6f) * (1.0f / 1433.6f); // (2i+0.4C)/(1.4C)
        float scale = exp2f(power * log2f(sv));
        float invf  = exp2f((float)i * (-13.287712379549449f / 512.0f)); // 10000^(-i/512)
        float ang   = (float)t * invf;
        float sn, cs;
        sincosf(ang, &sn, &cs);
        float rs = 1.0f / scale;
        float2 q = *(float2*)(row + 2*i);
        float2 k = *(float2*)(row + C_ + 2*i);
        float2 qo, ko;
        qo.x = q.x * (cs*scale) - q.y * (sn*scale);
        qo.y = q.y * (cs*scale) + q.x * (sn*scale);
        ko.x = k.x * (cs*rs) - k.y * (sn*rs);
        ko.y = k.y * (cs*rs) + k.x * (sn*rs);
        *(float2*)(row + 2*i) = qo;
        *(float2*)(row + C_ + 2*i) = ko;
    }
}

// ---------------- exact GELU in-place on ff region of qkvff ----------------
__global__ __launch_bounds__(256) void gelu_kernel(float* __restrict__ qkvff) {
    float* row = qkvff + (size_t)blockIdx.x * FC_ + 3*C_;
    for (int i = threadIdx.x; i < 512; i += 256) {       // 2048 floats = 512 float4
        float4 v = ((float4*)row)[i];
        v.x = 0.5f * v.x * (1.0f + erff(v.x * 0.70710678118f));
        v.y = 0.5f * v.y * (1.0f + erff(v.y * 0.70710678118f));
        v.z = 0.5f * v.z * (1.0f + erff(v.z * 0.70710678118f));
        v.w = 0.5f * v.w * (1.0f + erff(v.w * 0.70710678118f));
        ((float4*)row)[i] = v;
    }
}

// ---------------- generic fp32 GEMM: C = A(MxK) @ W(NxK)^T, tile 128x128, BK=16 ----
// EPI: 0 = none, 1 = silu(acc + bias), 2 = acc + bias + add1 + add2
template<int EPI>
__global__ __launch_bounds__(256) void gemm_kernel(const float* __restrict__ A, int lda,
                                                   const float* __restrict__ W, int ldw,
                                                   float* __restrict__ Cmat, int ldc, int K,
                                                   const float* __restrict__ bias,
                                                   const float* __restrict__ add1,
                                                   const float* __restrict__ add2) {
    __shared__ __align__(16) float As[16][132];
    __shared__ __align__(16) float Ws[16][132];
    int tid = threadIdx.x;
    int m0 = blockIdx.y * 128, n0 = blockIdx.x * 128;
    int tx = tid & 15, ty = tid >> 4;
    int sr = tid >> 2, sq = tid & 3;
    float acc[8][8] = {};
    const float* Abase = A + (size_t)(m0 + sr) * lda + sq * 4;
    const float* Wbase = W + (size_t)(n0 + sr) * ldw + sq * 4;
    for (int k0 = 0; k0 < K; k0 += 16) {
        float4 a0 = *(const float4*)(Abase + k0);
        float4 a1 = *(const float4*)(Abase + k0 + (size_t)64 * lda);
        float4 b0 = *(const float4*)(Wbase + k0);
        float4 b1 = *(const float4*)(Wbase + k0 + (size_t)64 * ldw);
        __syncthreads();
        int kk = sq * 4;
        As[kk+0][sr]    = a0.x; As[kk+1][sr]    = a0.y; As[kk+2][sr]    = a0.z; As[kk+3][sr]    = a0.w;
        As[kk+0][sr+64] = a1.x; As[kk+1][sr+64] = a1.y; As[kk+2][sr+64] = a1.z; As[kk+3][sr+64] = a1.w;
        Ws[kk+0][sr]    = b0.x; Ws[kk+1][sr]    = b0.y; Ws[kk+2][sr]    = b0.z; Ws[kk+3][sr]    = b0.w;
        Ws[kk+0][sr+64] = b1.x; Ws[kk+1][sr+64] = b1.y; Ws[kk+2][sr+64] = b1.z; Ws[kk+3][sr+64] = b1.w;
        __syncthreads();
        #pragma unroll
        for (int k = 0; k < 16; ++k) {
            float4 aa0 = *(const float4*)&As[k][ty*8];
            float4 aa1 = *(const float4*)&As[k][ty*8+4];
            float4 bb0 = *(const float4*)&Ws[k][tx*8];
            float4 bb1 = *(const float4*)&Ws[k][tx*8+4];
            float av[8] = {aa0.x,aa0.y,aa0.z,aa0.w,aa1.x,aa1.y,aa1.z,aa1.w};
            float bv[8] = {bb0.x,bb0.y,bb0.z,bb0.w,bb1.x,bb1.y,bb1.z,bb1.w};
            #pragma unroll
            for (int i = 0; i < 8; ++i)
                #pragma unroll
                for (int j = 0; j < 8; ++j)
                    acc[i][j] = fmaf(av[i], bv[j], acc[i][j]);
        }
    }
    #pragma unroll
    for (int i = 0; i < 8; ++i) {
        size_t r = (size_t)(m0 + ty*8 + i);
        int col0 = n0 + tx*8;
        float* crow = Cmat + r * ldc + col0;
        float out[8];
        #pragma unroll
        for (int j = 0; j < 8; ++j) {
            float v = acc[i][j];
            if (EPI == 1) {
                float s = v + bias[col0 + j];
                v = s / (1.0f + expf(-s));
            } else if (EPI == 2) {
                v += bias[col0 + j] + add1[r * ldc + col0 + j] + add2[r * ldc + col0 + j];
            }
            out[j] = v;
        }
        *(float4*)crow       = make_float4(out[0], out[1], out[2], out[3]);
        *(float4*)(crow + 4) = make_float4(out[4], out[5], out[6], out[7]);
    }
}

// ---------------- retention attention (causal + per-head decay) ----------------
// One block per (b, h, 64-row q tile). LDS: q/k/v/scores 64x64 fp32, XOR-swizzled.
__device__ __forceinline__ int swz(int r, int fc) {
    return (r << 6) + (((fc ^ (r >> 2)) & 15) << 2);   // float index of float4 block start
}

__global__ __launch_bounds__(256) void attn_kernel(const float* __restrict__ qkvff,
                                                   float* __restrict__ y) {
    __shared__ __align__(16) float qs[64*64];
    __shared__ __align__(16) float ks[64*64];
    __shared__ __align__(16) float vs[64*64];
    __shared__ __align__(16) float sm[64*64];
    int tt = blockIdx.x, h = blockIdx.y, b = blockIdx.z;
    int t0 = tt * 64;
    const float* base = qkvff + (size_t)b * T_ * FC_ + h * HD_;
    int tid = threadIdx.x, tx = tid & 15, ty = tid >> 4;
    int lr = tid >> 2, lq = tid & 3;
    // load q tile (rows t0..t0+63, 64 channels of this head)
    #pragma unroll
    for (int j = 0; j < 4; ++j) {
        int c4 = lq + 4*j;
        *(float4*)&qs[swz(lr, c4)] = *(const float4*)(base + (size_t)(t0 + lr) * FC_ + c4*4);
    }
    float lg2g = log2f(1.0f - exp2f(-5.0f - (float)h));
    float acc[4][4] = {};
    for (int st = 0; st <= tt; ++st) {
        int s0 = st * 64;
        __syncthreads();   // previous tile's PV reads done before overwrite
        #pragma unroll
        for (int j = 0; j < 4; ++j) {
            int c4 = lq + 4*j;
            const float* krow = base + (size_t)(s0 + lr) * FC_ + C_ + c4*4;
            *(float4*)&ks[swz(lr, c4)] = *(const float4*)krow;
            *(float4*)&vs[swz(lr, c4)] = *(const float4*)(krow + C_);
        }
        __syncthreads();
        // QK^T: sc[i][j] = q[t0+4ty+i] . k[s0+4tx+j]
        float sc[4][4] = {};
        #pragma unroll
        for (int dq = 0; dq < 16; ++dq) {
            float4 qv[4], kv[4];
            #pragma unroll
            for (int i = 0; i < 4; ++i) qv[i] = *(const float4*)&qs[swz(4*ty+i, dq)];
            #pragma unroll
            for (int j = 0; j < 4; ++j) kv[j] = *(const float4*)&ks[swz(4*tx+j, dq)];
            #pragma unroll
            for (int i = 0; i < 4; ++i)
                #pragma unroll
                for (int j = 0; j < 4; ++j)
                    sc[i][j] += qv[i].x*kv[j].x + qv[i].y*kv[j].y
                              + qv[i].z*kv[j].z + qv[i].w*kv[j].w;
        }
        // decay * hd^-0.5, causal mask; write scores to LDS
        #pragma unroll
        for (int i = 0; i < 4; ++i) {
            int tpos = t0 + 4*ty + i;
            float4 srow;
            float* sp = &srow.x;
            #pragma unroll
            for (int j = 0; j < 4; ++j) {
                int diff = tpos - (s0 + 4*tx + j);
                float w = (diff >= 0) ? exp2f(lg2g * (float)diff) * 0.125f : 0.0f;
                sp[j] = sc[i][j] * w;
            }
            *(float4*)&sm[swz(4*ty+i, tx)] = srow;
        }
        __syncthreads();
        // PV: acc[i][:] += scores[t][s] * v[s][d], d-block = tx
        #pragma unroll
        for (int cq = 0; cq < 16; ++cq) {
            float4 sv[4], vv[4];
            #pragma unroll
            for (int i = 0; i < 4; ++i) sv[i] = *(const float4*)&sm[swz(4*ty+i, cq)];
            #pragma unroll
            for (int e = 0; e < 4; ++e) vv[e] = *(const float4*)&vs[swz(4*cq+e, tx)];
            #pragma unroll
            for (int i = 0; i < 4; ++i) {
                acc[i][0] += sv[i].x*vv[0].x + sv[i].y*vv[1].x + sv[i].z*vv[2].x + sv[i].w*vv[3].x;
                acc[i][1] += sv[i].x*vv[0].y + sv[i].y*vv[1].y + sv[i].z*vv[2].y + sv[i].w*vv[3].y;
                acc[i][2] += sv[i].x*vv[0].z + sv[i].y*vv[1].z + sv[i].z*vv[2].z + sv[i].w*vv[3].z;
                acc[i][3] += sv[i].x*vv[0].w + sv[i].y*vv[1].w + sv[i].z*vv[2].w + sv[i].w*vv[3].w;
            }
        }
    }
    #pragma unroll
    for (int i = 0; i < 4; ++i) {
        int t = t0 + 4*ty + i;
        float4 o = make_float4(acc[i][0], acc[i][1], acc[i][2], acc[i][3]);
        *(float4*)(y + ((size_t)(b*T_ + t)) * C_ + h*HD_ + 4*tx) = o;
    }
}

// ---------------- GroupNorm(per token, per head) * silu-gate, in-place into gate ----
__global__ __launch_bounds__(256) void gn_gate_kernel(const float* __restrict__ y,
                                                      float* __restrict__ gate,
                                                      const float* __restrict__ gn_w,
                                                      const float* __restrict__ gn_b) {
    int bt = blockIdx.x;
    int tid = threadIdx.x;            // thread covers channels 4*tid..4*tid+3; group = tid/16
    float4 v = ((const float4*)(y + (size_t)bt * C_))[tid];
    float s1 = v.x + v.y + v.z + v.w;
    float s2 = v.x*v.x + v.y*v.y + v.z*v.z + v.w*v.w;
    #pragma unroll
    for (int m = 1; m < 16; m <<= 1) { s1 += __shfl_xor(s1, m); s2 += __shfl_xor(s2, m); }
    float mu   = s1 * (1.0f/64.0f);
    float var  = s2 * (1.0f/64.0f) - mu*mu;
    float rstd = rsqrtf(var + 1e-5f);
    float4 w  = ((const float4*)gn_w)[tid];
    float4 bb = ((const float4*)gn_b)[tid];
    float4 g  = ((const float4*)(gate + (size_t)bt * C_))[tid];
    float4 o;
    o.x = ((v.x - mu)*rstd*w.x + bb.x) * g.x;
    o.y = ((v.y - mu)*rstd*w.y + bb.y) * g.y;
    o.z = ((v.z - mu)*rstd*w.z + bb.z) * g.z;
    o.w = ((v.w - mu)*rstd*w.w + bb.w) * g.w;
    ((float4*)(gate + (size_t)bt * C_))[tid] = o;
}

extern "C" void kernel_launch(void* const* d_in, const int* in_sizes, int n_in,
                              void* d_out, int out_size, void* d_ws, size_t ws_size,
                              hipStream_t stream) {
    (void)in_sizes; (void)n_in; (void)out_size; (void)ws_size;
    const float* x       = (const float*)d_in[0];
    const float* w_qkvff = (const float*)d_in[1];
    const float* w_gated = (const float*)d_in[2];
    const float* b_gated = (const float*)d_in[3];
    const float* w_proj  = (const float*)d_in[4];
    const float* b_proj  = (const float*)d_in[5];
    const float* gn_w    = (const float*)d_in[6];
    const float* gn_b    = (const float*)d_in[7];
    const float* w_ff    = (const float*)d_in[8];
    const float* rms_w   = (const float*)d_in[9];
    float* out = (float*)d_out;

    const size_t NTOK = (size_t)B_ * T_;                 // 4096
    float* buf0  = (float*)d_ws;                          // xn, later ff_out
    float* buf1  = buf0 + NTOK * C_;                      // y (attention out)
    float* buf2  = buf1 + NTOK * C_;                      // gate -> ygated (in place)
    float* qkvff = buf2 + NTOK * C_;                      // 4096 x 5120

    // 1. RMSNorm
    rmsnorm_kernel<<<4096, 256, 0, stream>>>(x, rms_w, buf0);
    // 2. qkvff = xn @ w_qkvff^T   (M=4096, N=5120, K=1024)
    gemm_kernel<0><<<dim3(40, 32), 256, 0, stream>>>(buf0, C_, w_qkvff, C_, qkvff, FC_, C_,
                                                     nullptr, nullptr, nullptr);
    // 3. xpos rotary on q,k (in place)
    xpos_kernel<<<4096, 256, 0, stream>>>(qkvff);
    // 4. exact gelu on ff (in place)
    gelu_kernel<<<4096, 256, 0, stream>>>(qkvff);
    // 5. retention attention -> y
    attn_kernel<<<dim3(32, 16, 2), 256, 0, stream>>>(qkvff, buf1);
    // 6. gate = silu(x @ w_gated^T + b_gated)   (M=4096, N=1024, K=1024)
    gemm_kernel<1><<<dim3(8, 32), 256, 0, stream>>>(x, C_, w_gated, C_, buf2, C_, C_,
                                                    b_gated, nullptr, nullptr);
    // 7. ygated = gate * (GN(y)*gn_w + gn_b)
    gn_gate_kernel<<<4096, 256, 0, stream>>>(buf1, buf2, gn_w, gn_b);
    // 8. ff_out = gelu(ff) @ w_ff^T   (M=4096, N=1024, K=2048)
    gemm_kernel<0><<<dim3(8, 32), 256, 0, stream>>>(qkvff + 3*C_, FC_, w_ff, 2*C_, buf0, C_, 2*C_,
                                                    nullptr, nullptr, nullptr);
    // 9. out = x + ff_out + (ygated @ w_proj^T + b_proj)
    gemm_kernel<2><<<dim3(8, 32), 256, 0, stream>>>(buf2, C_, w_proj, C_, out, C_, C_,
                                                    b_proj, x, buf0);
}

// Round 3
// 1226.630 us; speedup vs baseline: 1.7183x; 1.7183x over previous
//
#include <hip/hip_runtime.h>
#include <math.h>

#define B_  2
#define T_  2048
#define C_  1024
#define H_  16
#define HD_ 64
#define FC_ 5120   // 5*C

typedef __attribute__((ext_vector_type(8))) short  s16x8;
typedef __attribute__((ext_vector_type(4))) float  f32x4;
typedef __attribute__((ext_vector_type(2))) unsigned short u16x2;
typedef __attribute__((ext_vector_type(4))) unsigned short u16x4;
typedef __attribute__((ext_vector_type(8))) unsigned short u16x8;

__device__ __forceinline__ ushort f2bf(float f) {
    union { float f; unsigned u; } v; v.f = f;
    unsigned r = v.u + 0x7FFFu + ((v.u >> 16) & 1u);   // round-to-nearest-even
    return (ushort)(r >> 16);
}

// ---------------- RMSNorm: xn = x / max(||x||*C^-0.5, 1e-8) * rms_w ----------------
__global__ __launch_bounds__(256) void rmsnorm_kernel(const float* __restrict__ x,
                                                      const float* __restrict__ rms_w,
                                                      float* __restrict__ xn) {
    int row = blockIdx.x;
    int tid = threadIdx.x;
    float4 v = ((const float4*)(x + (size_t)row * C_))[tid];
    float ss = v.x*v.x + v.y*v.y + v.z*v.z + v.w*v.w;
    #pragma unroll
    for (int m = 32; m >= 1; m >>= 1) ss += __shfl_xor(ss, m);
    __shared__ float wsum[4];
    if ((tid & 63) == 0) wsum[tid >> 6] = ss;
    __syncthreads();
    float tot = wsum[0] + wsum[1] + wsum[2] + wsum[3];
    float nrm = sqrtf(tot) * 0.03125f;
    float inv = 1.0f / fmaxf(nrm, 1e-8f);
    float4 w = ((const float4*)rms_w)[tid];
    float4 o;
    o.x = v.x * inv * w.x;  o.y = v.y * inv * w.y;
    o.z = v.z * inv * w.z;  o.w = v.w * inv * w.w;
    ((float4*)(xn + (size_t)row * C_))[tid] = o;
}

// ---- xpos rotary + decay pre-scale + bf16 pack:  qkvb = [q*0.125*g^t | k*g^-t | v] ----
__global__ __launch_bounds__(256) void xpos_bf16_kernel(const float* __restrict__ qkvff,
                                                        ushort* __restrict__ qkv) {
    int bt = blockIdx.x;
    int t = bt & (T_ - 1);
    float tf = (float)t;
    const float* row = qkvff + (size_t)bt * FC_;
    ushort* orow = qkv + (size_t)bt * 3072;
    float power = (tf - 1024.0f) * (1.0f / 512.0f);
    for (int i = threadIdx.x; i < 512; i += 256) {       // pair index, half=512
        float sv    = (2.0f * (float)i + 409.6f) * (1.0f / 1433.6f);
        float scale = exp2f(power * log2f(sv));
        float invf  = exp2f((float)i * (-13.287712379549449f / 512.0f));
        float ang   = tf * invf;
        float sn, cs;
        sincosf(ang, &sn, &cs);
        float rs = 1.0f / scale;
        int hh = i >> 5;                                  // head of this pair
        float lg2g = log2f(1.0f - exp2f(-5.0f - (float)hh));
        float gq = exp2f(lg2g * tf) * 0.125f;             // 0.125 * gamma^t
        float gk = exp2f(-lg2g * tf);                     // gamma^-t
        float2 q = *(const float2*)(row + 2*i);
        float2 k = *(const float2*)(row + C_ + 2*i);
        float qox = (q.x*(cs*scale) - q.y*(sn*scale)) * gq;
        float qoy = (q.y*(cs*scale) + q.x*(sn*scale)) * gq;
        float kox = (k.x*(cs*rs) - k.y*(sn*rs)) * gk;
        float koy = (k.y*(cs*rs) + k.x*(sn*rs)) * gk;
        u16x2 qo; qo[0] = f2bf(qox); qo[1] = f2bf(qoy);
        u16x2 ko; ko[0] = f2bf(kox); ko[1] = f2bf(koy);
        *(u16x2*)(orow + 2*i) = qo;
        *(u16x2*)(orow + 1024 + 2*i) = ko;
    }
    {   // v: straight bf16 convert
        int c = threadIdx.x * 4;
        float4 v = *(const float4*)(row + 2*C_ + c);
        u16x4 o; o[0] = f2bf(v.x); o[1] = f2bf(v.y); o[2] = f2bf(v.z); o[3] = f2bf(v.w);
        *(u16x4*)(orow + 2048 + c) = o;
    }
}

// ---------------- exact GELU in-place on ff region of qkvff ----------------
__global__ __launch_bounds__(256) void gelu_kernel(float* __restrict__ qkvff) {
    float* row = qkvff + (size_t)blockIdx.x * FC_ + 3*C_;
    for (int i = threadIdx.x; i < 512; i += 256) {
        float4 v = ((float4*)row)[i];
        v.x = 0.5f * v.x * (1.0f + erff(v.x * 0.70710678118f));
        v.y = 0.5f * v.y * (1.0f + erff(v.y * 0.70710678118f));
        v.z = 0.5f * v.z * (1.0f + erff(v.z * 0.70710678118f));
        v.w = 0.5f * v.w * (1.0f + erff(v.w * 0.70710678118f));
        ((float4*)row)[i] = v;
    }
}

// ---------------- generic fp32 GEMM: C = A(MxK) @ W(NxK)^T, tile 128x128, BK=16 ----
template<int EPI>
__global__ __launch_bounds__(256) void gemm_kernel(const float* __restrict__ A, int lda,
                                                   const float* __restrict__ W, int ldw,
                                                   float* __restrict__ Cmat, int ldc, int K,
                                                   const float* __restrict__ bias,
                                                   const float* __restrict__ add1,
                                                   const float* __restrict__ add2) {
    __shared__ __align__(16) float As[16][132];
    __shared__ __align__(16) float Ws[16][132];
    int tid = threadIdx.x;
    int m0 = blockIdx.y * 128, n0 = blockIdx.x * 128;
    int tx = tid & 15, ty = tid >> 4;
    int sr = tid >> 2, sq = tid & 3;
    float acc[8][8] = {};
    const float* Abase = A + (size_t)(m0 + sr) * lda + sq * 4;
    const float* Wbase = W + (size_t)(n0 + sr) * ldw + sq * 4;
    for (int k0 = 0; k0 < K; k0 += 16) {
        float4 a0 = *(const float4*)(Abase + k0);
        float4 a1 = *(const float4*)(Abase + k0 + (size_t)64 * lda);
        float4 b0 = *(const float4*)(Wbase + k0);
        float4 b1 = *(const float4*)(Wbase + k0 + (size_t)64 * ldw);
        __syncthreads();
        int kk = sq * 4;
        As[kk+0][sr]    = a0.x; As[kk+1][sr]    = a0.y; As[kk+2][sr]    = a0.z; As[kk+3][sr]    = a0.w;
        As[kk+0][sr+64] = a1.x; As[kk+1][sr+64] = a1.y; As[kk+2][sr+64] = a1.z; As[kk+3][sr+64] = a1.w;
        Ws[kk+0][sr]    = b0.x; Ws[kk+1][sr]    = b0.y; Ws[kk+2][sr]    = b0.z; Ws[kk+3][sr]    = b0.w;
        Ws[kk+0][sr+64] = b1.x; Ws[kk+1][sr+64] = b1.y; Ws[kk+2][sr+64] = b1.z; Ws[kk+3][sr+64] = b1.w;
        __syncthreads();
        #pragma unroll
        for (int k = 0; k < 16; ++k) {
            float4 aa0 = *(const float4*)&As[k][ty*8];
            float4 aa1 = *(const float4*)&As[k][ty*8+4];
            float4 bb0 = *(const float4*)&Ws[k][tx*8];
            float4 bb1 = *(const float4*)&Ws[k][tx*8+4];
            float av[8] = {aa0.x,aa0.y,aa0.z,aa0.w,aa1.x,aa1.y,aa1.z,aa1.w};
            float bv[8] = {bb0.x,bb0.y,bb0.z,bb0.w,bb1.x,bb1.y,bb1.z,bb1.w};
            #pragma unroll
            for (int i = 0; i < 8; ++i)
                #pragma unroll
                for (int j = 0; j < 8; ++j)
                    acc[i][j] = fmaf(av[i], bv[j], acc[i][j]);
        }
    }
    #pragma unroll
    for (int i = 0; i < 8; ++i) {
        size_t r = (size_t)(m0 + ty*8 + i);
        int col0 = n0 + tx*8;
        float* crow = Cmat + r * ldc + col0;
        float out[8];
        #pragma unroll
        for (int j = 0; j < 8; ++j) {
            float v = acc[i][j];
            if (EPI == 1) {
                float s = v + bias[col0 + j];
                v = s / (1.0f + expf(-s));
            } else if (EPI == 2) {
                v += bias[col0 + j] + add1[r * ldc + col0 + j] + add2[r * ldc + col0 + j];
            }
            out[j] = v;
        }
        *(float4*)crow       = make_float4(out[0], out[1], out[2], out[3]);
        *(float4*)(crow + 4) = make_float4(out[4], out[5], out[6], out[7]);
    }
}

// ---------------- retention attention, bf16 MFMA 16x16x32 ----------------
// decay folded into pre-scaled q,k (gamma^t / gamma^-s); only diagonal tiles masked.
// LDS: K [s][d] bf16 swizzled; V^T [d][s] bf16 swizzled; per-wave S [t][s] bf16.
__global__ __launch_bounds__(256) void attn_mfma_kernel(const ushort* __restrict__ qkv,
                                                        float* __restrict__ y) {
    __shared__ ushort Ks[64*64];
    __shared__ ushort Vt[64*64];
    __shared__ ushort Ss[4][16*64];
    int tt = 31 - (int)blockIdx.x;              // big tiles first (load balance)
    int h = blockIdx.y, b = blockIdx.z;
    int t0 = tt * 64;
    int tid = threadIdx.x;
    int wave = tid >> 6, lane = tid & 63;
    int lo = lane & 15, hi = lane >> 4;
    const size_t bT = (size_t)b * T_;

    // Q fragments in registers: A[row=lo][d = hi*8+j], frag1: d+=32
    s16x8 qf0, qf1;
    {
        const ushort* qrow = qkv + (bT + t0 + wave*16 + lo) * 3072 + h*64;
        qf0 = *(const s16x8*)(qrow + hi*8);
        qf1 = *(const s16x8*)(qrow + 32 + hi*8);
    }
    f32x4 accy[4] = {};

    int kr = tid >> 2, kc = tid & 3;                 // K staging: row kr, 2x16B chunks
    int vd0 = (tid & 15) * 4, vs0 = (tid >> 4) * 4;  // V staging: 4x4 block transpose

    for (int st = 0; st <= tt; ++st) {
        int s0 = st * 64;
        __syncthreads();
        {   // stage K[s][d] (swizzled rows)
            const ushort* src = qkv + (bT + s0 + kr) * 3072 + 1024 + h*64;
            u16x8 a = *(const u16x8*)(src + kc*8);
            u16x8 c2 = *(const u16x8*)(src + (kc+4)*8);
            int base = kr * 128, sw = (kr & 7) << 4;
            *(u16x8*)((char*)Ks + ((base + kc*16) ^ sw))     = a;
            *(u16x8*)((char*)Ks + ((base + (kc+4)*16) ^ sw)) = c2;
        }
        {   // stage V^T[d][s] via 4x4 register transpose
            const ushort* src = qkv + (bT + s0 + vs0) * 3072 + 2048 + h*64 + vd0;
            u16x4 l0 = *(const u16x4*)(src);
            u16x4 l1 = *(const u16x4*)(src + 3072);
            u16x4 l2 = *(const u16x4*)(src + 2*3072);
            u16x4 l3 = *(const u16x4*)(src + 3*3072);
            #pragma unroll
            for (int i = 0; i < 4; ++i) {
                u16x4 o; o[0] = l0[i]; o[1] = l1[i]; o[2] = l2[i]; o[3] = l3[i];
                int d = vd0 + i;
                *(u16x4*)((char*)Vt + ((d*128 + vs0*2) ^ ((d & 7) << 4))) = o;
            }
        }
        __syncthreads();
        // S = Q @ K^T   (decay already folded in; accumulate fp32)
        f32x4 sacc[4] = {};
        #pragma unroll
        for (int sn = 0; sn < 4; ++sn) {
            int srow = sn*16 + lo;
            int rb = srow * 128, sw = (srow & 7) << 4;
            s16x8 kf0 = *(const s16x8*)((const char*)Ks + ((rb + hi*16) ^ sw));
            s16x8 kf1 = *(const s16x8*)((const char*)Ks + ((rb + 64 + hi*16) ^ sw));
            sacc[sn] = __builtin_amdgcn_mfma_f32_16x16x32_bf16(qf0, kf0, sacc[sn], 0, 0, 0);
            sacc[sn] = __builtin_amdgcn_mfma_f32_16x16x32_bf16(qf1, kf1, sacc[sn], 0, 0, 0);
        }
        // mask diagonal tile, convert to bf16, park in wave-private LDS (A-frag layout)
        #pragma unroll
        for (int sn = 0; sn < 4; ++sn) {
            int sl = sn*16 + lo;
            #pragma unroll
            for (int r = 0; r < 4; ++r) {
                float v = sacc[sn][r];
                if (st == tt && sl > wave*16 + hi*4 + r) v = 0.0f;
                int tq = hi*4 + r;
                *(ushort*)((char*)Ss[wave] + ((tq*128 + sl*2) ^ ((tq & 7) << 4))) = f2bf(v);
            }
        }
        // PV: y += S @ V
        s16x8 sa0 = *(const s16x8*)((const char*)Ss[wave] + ((lo*128 + hi*16) ^ ((lo & 7) << 4)));
        s16x8 sa1 = *(const s16x8*)((const char*)Ss[wave] + ((lo*128 + 64 + hi*16) ^ ((lo & 7) << 4)));
        #pragma unroll
        for (int dn = 0; dn < 4; ++dn) {
            int d = dn*16 + lo;
            int rb = d * 128, sw = (d & 7) << 4;
            s16x8 vf0 = *(const s16x8*)((const char*)Vt + ((rb + hi*16) ^ sw));
            s16x8 vf1 = *(const s16x8*)((const char*)Vt + ((rb + 64 + hi*16) ^ sw));
            accy[dn] = __builtin_amdgcn_mfma_f32_16x16x32_bf16(sa0, vf0, accy[dn], 0, 0, 0);
            accy[dn] = __builtin_amdgcn_mfma_f32_16x16x32_bf16(sa1, vf1, accy[dn], 0, 0, 0);
        }
    }
    // epilogue: C-frag row = 4*hi + r, col = dn*16 + lo
    #pragma unroll
    for (int dn = 0; dn < 4; ++dn) {
        #pragma unroll
        for (int r = 0; r < 4; ++r) {
            int t = t0 + wave*16 + hi*4 + r;
            y[(bT + t) * C_ + h*64 + dn*16 + lo] = accy[dn][r];
        }
    }
}

// ---------------- GroupNorm(per token, per head) * silu-gate ----------------
__global__ __launch_bounds__(256) void gn_gate_kernel(const float* __restrict__ y,
                                                      float* __restrict__ gate,
                                                      const float* __restrict__ gn_w,
                                                      const float* __restrict__ gn_b) {
    int bt = blockIdx.x;
    int tid = threadIdx.x;
    float4 v = ((const float4*)(y + (size_t)bt * C_))[tid];
    float s1 = v.x + v.y + v.z + v.w;
    float s2 = v.x*v.x + v.y*v.y + v.z*v.z + v.w*v.w;
    #pragma unroll
    for (int m = 1; m < 16; m <<= 1) { s1 += __shfl_xor(s1, m); s2 += __shfl_xor(s2, m); }
    float mu   = s1 * (1.0f/64.0f);
    float var  = s2 * (1.0f/64.0f) - mu*mu;
    float rstd = rsqrtf(var + 1e-5f);
    float4 w  = ((const float4*)gn_w)[tid];
    float4 bb = ((const float4*)gn_b)[tid];
    float4 g  = ((const float4*)(gate + (size_t)bt * C_))[tid];
    float4 o;
    o.x = ((v.x - mu)*rstd*w.x + bb.x) * g.x;
    o.y = ((v.y - mu)*rstd*w.y + bb.y) * g.y;
    o.z = ((v.z - mu)*rstd*w.z + bb.z) * g.z;
    o.w = ((v.w - mu)*rstd*w.w + bb.w) * g.w;
    ((float4*)(gate + (size_t)bt * C_))[tid] = o;
}

extern "C" void kernel_launch(void* const* d_in, const int* in_sizes, int n_in,
                              void* d_out, int out_size, void* d_ws, size_t ws_size,
                              hipStream_t stream) {
    (void)in_sizes; (void)n_in; (void)out_size; (void)ws_size;
    const float* x       = (const float*)d_in[0];
    const float* w_qkvff = (const float*)d_in[1];
    const float* w_gated = (const float*)d_in[2];
    const float* b_gated = (const float*)d_in[3];
    const float* w_proj  = (const float*)d_in[4];
    const float* b_proj  = (const float*)d_in[5];
    const float* gn_w    = (const float*)d_in[6];
    const float* gn_b    = (const float*)d_in[7];
    const float* w_ff    = (const float*)d_in[8];
    const float* rms_w   = (const float*)d_in[9];
    float* out = (float*)d_out;

    const size_t NTOK = (size_t)B_ * T_;                  // 4096
    float* buf0  = (float*)d_ws;                          // xn, later ff_out
    float* buf1  = buf0 + NTOK * C_;                      // y (attention out)
    float* buf2  = buf1 + NTOK * C_;                      // gate -> ygated (in place)
    float* qkvff = buf2 + NTOK * C_;                      // 4096 x 5120 fp32
    ushort* qkvb = (ushort*)(qkvff + NTOK * FC_);         // 4096 x 3072 bf16 (scaled q,k + v)

    rmsnorm_kernel<<<4096, 256, 0, stream>>>(x, rms_w, buf0);
    gemm_kernel<0><<<dim3(40, 32), 256, 0, stream>>>(buf0, C_, w_qkvff, C_, qkvff, FC_, C_,
                                                     nullptr, nullptr, nullptr);
    xpos_bf16_kernel<<<4096, 256, 0, stream>>>(qkvff, qkvb);
    gelu_kernel<<<4096, 256, 0, stream>>>(qkvff);
    attn_mfma_kernel<<<dim3(32, 16, 2), 256, 0, stream>>>(qkvb, buf1);
    gemm_kernel<1><<<dim3(8, 32), 256, 0, stream>>>(x, C_, w_gated, C_, buf2, C_, C_,
                                                    b_gated, nullptr, nullptr);
    gn_gate_kernel<<<4096, 256, 0, stream>>>(buf1, buf2, gn_w, gn_b);
    gemm_kernel<0><<<dim3(8, 32), 256, 0, stream>>>(qkvff + 3*C_, FC_, w_ff, 2*C_, buf0, C_, 2*C_,
                                                    nullptr, nullptr, nullptr);
    gemm_kernel<2><<<dim3(8, 32), 256, 0, stream>>>(buf2, C_, w_proj, C_, out, C_, C_,
                                                    b_proj, x, buf0);
}

// Round 5
// 349.221 us; speedup vs baseline: 6.0355x; 3.5125x over previous
//
#include <hip/hip_runtime.h>
#include <math.h>

#define B_  2
#define T_  2048
#define C_  1024
#define H_  16
#define FC_ 5120   // 5*C

typedef __attribute__((ext_vector_type(8))) short  s16x8;
typedef __attribute__((ext_vector_type(4))) float  f32x4;
typedef __attribute__((ext_vector_type(2))) unsigned short u16x2;
typedef __attribute__((ext_vector_type(4))) unsigned short u16x4;
typedef __attribute__((ext_vector_type(8))) unsigned short u16x8;

__device__ __forceinline__ ushort f2bf(float f) {
    union { float f; unsigned u; } v; v.f = f;
    unsigned r = v.u + 0x7FFFu + ((v.u >> 16) & 1u);   // round-to-nearest-even
    return (ushort)(r >> 16);
}

// ---------------- fp32 -> bf16 bulk convert (8 elems/thread) ----------------
__global__ __launch_bounds__(256) void cvt_bf16_kernel(const float* __restrict__ src,
                                                       ushort* __restrict__ dst, int n8) {
    int i = blockIdx.x * 256 + threadIdx.x;
    if (i >= n8) return;
    float4 a = ((const float4*)src)[2*i];
    float4 b = ((const float4*)src)[2*i + 1];
    u16x8 o;
    o[0] = f2bf(a.x); o[1] = f2bf(a.y); o[2] = f2bf(a.z); o[3] = f2bf(a.w);
    o[4] = f2bf(b.x); o[5] = f2bf(b.y); o[6] = f2bf(b.z); o[7] = f2bf(b.w);
    *(u16x8*)(dst + 8*i) = o;
}

// ---------------- RMSNorm -> bf16: xn = x / max(||x||*C^-0.5, 1e-8) * rms_w ----------
__global__ __launch_bounds__(256) void rmsnorm_kernel(const float* __restrict__ x,
                                                      const float* __restrict__ rms_w,
                                                      ushort* __restrict__ xn) {
    int row = blockIdx.x;
    int tid = threadIdx.x;
    float4 v = ((const float4*)(x + (size_t)row * C_))[tid];
    float ss = v.x*v.x + v.y*v.y + v.z*v.z + v.w*v.w;
    #pragma unroll
    for (int m = 32; m >= 1; m >>= 1) ss += __shfl_xor(ss, m);
    __shared__ float wsum[4];
    if ((tid & 63) == 0) wsum[tid >> 6] = ss;
    __syncthreads();
    float tot = wsum[0] + wsum[1] + wsum[2] + wsum[3];
    float nrm = sqrtf(tot) * 0.03125f;
    float inv = 1.0f / fmaxf(nrm, 1e-8f);
    float4 w = ((const float4*)rms_w)[tid];
    u16x4 o;
    o[0] = f2bf(v.x * inv * w.x);  o[1] = f2bf(v.y * inv * w.y);
    o[2] = f2bf(v.z * inv * w.z);  o[3] = f2bf(v.w * inv * w.w);
    *(u16x4*)(xn + (size_t)row * C_ + 4*tid) = o;
}

// ---- xpos rotary + decay pre-scale + bf16 pack:  qkvb = [q*0.125*g^t | k*g^-t | v] ----
__global__ __launch_bounds__(256) void xpos_bf16_kernel(const float* __restrict__ qkvff,
                                                        ushort* __restrict__ qkv) {
    int bt = blockIdx.x;
    int t = bt & (T_ - 1);
    float tf = (float)t;
    const float* row = qkvff + (size_t)bt * FC_;
    ushort* orow = qkv + (size_t)bt * 3072;
    float power = (tf - 1024.0f) * (1.0f / 512.0f);
    for (int i = threadIdx.x; i < 512; i += 256) {       // pair index, half=512
        float sv    = (2.0f * (float)i + 409.6f) * (1.0f / 1433.6f);
        float scale = exp2f(power * log2f(sv));
        float invf  = exp2f((float)i * (-13.287712379549449f / 512.0f));
        float ang   = tf * invf;
        float sn, cs;
        sincosf(ang, &sn, &cs);
        float rs = 1.0f / scale;
        int hh = i >> 5;                                  // head of this pair
        float lg2g = log2f(1.0f - exp2f(-5.0f - (float)hh));
        float gq = exp2f(lg2g * tf) * 0.125f;             // 0.125 * gamma^t
        float gk = exp2f(-lg2g * tf);                     // gamma^-t
        float2 q = *(const float2*)(row + 2*i);
        float2 k = *(const float2*)(row + C_ + 2*i);
        float qox = (q.x*(cs*scale) - q.y*(sn*scale)) * gq;
        float qoy = (q.y*(cs*scale) + q.x*(sn*scale)) * gq;
        float kox = (k.x*(cs*rs) - k.y*(sn*rs)) * gk;
        float koy = (k.y*(cs*rs) + k.x*(sn*rs)) * gk;
        u16x2 qo; qo[0] = f2bf(qox); qo[1] = f2bf(qoy);
        u16x2 ko; ko[0] = f2bf(kox); ko[1] = f2bf(koy);
        *(u16x2*)(orow + 2*i) = qo;
        *(u16x2*)(orow + 1024 + 2*i) = ko;
    }
    {   // v: straight bf16 convert
        int c = threadIdx.x * 4;
        float4 v = *(const float4*)(row + 2*C_ + c);
        u16x4 o; o[0] = f2bf(v.x); o[1] = f2bf(v.y); o[2] = f2bf(v.z); o[3] = f2bf(v.w);
        *(u16x4*)(orow + 2048 + c) = o;
    }
}

// ---------------- exact GELU on ff region of qkvff -> bf16 buffer ----------------
__global__ __launch_bounds__(256) void gelu_bf16_kernel(const float* __restrict__ qkvff,
                                                        ushort* __restrict__ ffb) {
    const float* row = qkvff + (size_t)blockIdx.x * FC_ + 3*C_;
    ushort* orow = ffb + (size_t)blockIdx.x * 2048;
    for (int i = threadIdx.x; i < 512; i += 256) {
        float4 v = ((const float4*)row)[i];
        u16x4 o;
        o[0] = f2bf(0.5f * v.x * (1.0f + erff(v.x * 0.70710678118f)));
        o[1] = f2bf(0.5f * v.y * (1.0f + erff(v.y * 0.70710678118f)));
        o[2] = f2bf(0.5f * v.z * (1.0f + erff(v.z * 0.70710678118f)));
        o[3] = f2bf(0.5f * v.w * (1.0f + erff(v.w * 0.70710678118f)));
        *(u16x4*)(orow + 4*i) = o;
    }
}

// ---------------- bf16 MFMA GEMM: C = A(MxK) @ W(NxK)^T ----------------
// 128x128 tile, BK=64, 4 waves (2x2), each wave 64x64 out = 4x4 x (16x16x32 MFMA).
// LDS tiles [128 rows][64 bf16], XOR-swizzled: byte ^= (row&7)<<4.
// EPI: 0 = plain fp32 store, 1 = silu(acc+bias), 2 = acc+bias+add1+add2
template<int EPI>
__global__ __launch_bounds__(256) void gemm_bf16_kernel(
        const ushort* __restrict__ A, int lda,
        const ushort* __restrict__ W, int ldw,
        float* __restrict__ Cmat, int ldc, int K,
        const float* __restrict__ bias,
        const float* __restrict__ add1,
        const float* __restrict__ add2) {
    __shared__ __align__(16) ushort As[128*64];
    __shared__ __align__(16) ushort Bs[128*64];
    int tid = threadIdx.x;
    int m0 = blockIdx.y * 128, n0 = blockIdx.x * 128;
    int wave = tid >> 6, lane = tid & 63;
    int lo = lane & 15, hi = lane >> 4;
    int wm = (wave >> 1) * 64, wn = (wave & 1) * 64;
    int srow = tid >> 3;          // staging row 0..31 (+32*i)
    int su   = tid & 7;           // 16B slot within row
    f32x4 acc[4][4] = {};

    u16x8 ra[4], rb[4];
    #pragma unroll
    for (int i = 0; i < 4; ++i) {                 // prologue: tile k0=0
        int row = srow + 32*i;
        ra[i] = *(const u16x8*)(A + (size_t)(m0 + row) * lda + su*8);
        rb[i] = *(const u16x8*)(W + (size_t)(n0 + row) * ldw + su*8);
    }
    for (int k0 = 0;;) {
        __syncthreads();                          // prev compute reads done
        #pragma unroll
        for (int i = 0; i < 4; ++i) {
            int row = srow + 32*i;
            int off = row*128 + ((su*16) ^ ((row & 7) << 4));
            *(u16x8*)((char*)As + off) = ra[i];
            *(u16x8*)((char*)Bs + off) = rb[i];
        }
        __syncthreads();
        k0 += 64;
        if (k0 < K) {                             // prefetch next tile (overlaps MFMA)
            #pragma unroll
            for (int i = 0; i < 4; ++i) {
                int row = srow + 32*i;
                ra[i] = *(const u16x8*)(A + (size_t)(m0 + row) * lda + k0 + su*8);
                rb[i] = *(const u16x8*)(W + (size_t)(n0 + row) * ldw + k0 + su*8);
            }
        }
        #pragma unroll
        for (int kc = 0; kc < 2; ++kc) {
            s16x8 af[4], bf[4];
            #pragma unroll
            for (int g = 0; g < 4; ++g) {
                int arow = wm + g*16 + lo;
                af[g] = *(const s16x8*)((const char*)As +
                         arow*128 + ((kc*64 + hi*16) ^ ((arow & 7) << 4)));
                int brow = wn + g*16 + lo;
                bf[g] = *(const s16x8*)((const char*)Bs +
                         brow*128 + ((kc*64 + hi*16) ^ ((brow & 7) << 4)));
            }
            #pragma unroll
            for (int mg = 0; mg < 4; ++mg)
                #pragma unroll
                for (int ng = 0; ng < 4; ++ng)
                    acc[mg][ng] = __builtin_amdgcn_mfma_f32_16x16x32_bf16(
                        af[mg], bf[ng], acc[mg][ng], 0, 0, 0);
        }
        if (k0 >= K) break;
    }
    // epilogue: C[row = hi*4+r][col = lo] per fragment
    #pragma unroll
    for (int mg = 0; mg < 4; ++mg) {
        #pragma unroll
        for (int r = 0; r < 4; ++r) {
            size_t m = (size_t)(m0 + wm + mg*16 + hi*4 + r);
            #pragma unroll
            for (int ng = 0; ng < 4; ++ng) {
                int n = n0 + wn + ng*16 + lo;
                float v = acc[mg][ng][r];
                if (EPI == 1) {
                    float s = v + bias[n];
                    v = s / (1.0f + expf(-s));
                } else if (EPI == 2) {
                    v += bias[n] + add1[m*ldc + n] + add2[m*ldc + n];
                }
                Cmat[m*ldc + n] = v;
            }
        }
    }
}

// ---------------- retention attention, bf16 MFMA 16x16x32 ----------------
__global__ __launch_bounds__(256) void attn_mfma_kernel(const ushort* __restrict__ qkv,
                                                        float* __restrict__ y) {
    __shared__ ushort Ks[64*64];
    __shared__ ushort Vt[64*64];
    __shared__ ushort Ss[4][16*64];
    int tt = 31 - (int)blockIdx.x;              // big tiles first (load balance)
    int h = blockIdx.y, b = blockIdx.z;
    int t0 = tt * 64;
    int tid = threadIdx.x;
    int wave = tid >> 6, lane = tid & 63;
    int lo = lane & 15, hi = lane >> 4;
    const size_t bT = (size_t)b * T_;

    s16x8 qf0, qf1;
    {
        const ushort* qrow = qkv + (bT + t0 + wave*16 + lo) * 3072 + h*64;
        qf0 = *(const s16x8*)(qrow + hi*8);
        qf1 = *(const s16x8*)(qrow + 32 + hi*8);
    }
    f32x4 accy[4] = {};

    int kr = tid >> 2, kc = tid & 3;
    int vd0 = (tid & 15) * 4, vs0 = (tid >> 4) * 4;

    for (int st = 0; st <= tt; ++st) {
        int s0 = st * 64;
        __syncthreads();
        {   // stage K[s][d] (swizzled rows)
            const ushort* src = qkv + (bT + s0 + kr) * 3072 + 1024 + h*64;
            u16x8 a = *(const u16x8*)(src + kc*8);
            u16x8 c2 = *(const u16x8*)(src + (kc+4)*8);
            int base = kr * 128, sw = (kr & 7) << 4;
            *(u16x8*)((char*)Ks + ((base + kc*16) ^ sw))     = a;
            *(u16x8*)((char*)Ks + ((base + (kc+4)*16) ^ sw)) = c2;
        }
        {   // stage V^T[d][s] via 4x4 register transpose
            const ushort* src = qkv + (bT + s0 + vs0) * 3072 + 2048 + h*64 + vd0;
            u16x4 l0 = *(const u16x4*)(src);
            u16x4 l1 = *(const u16x4*)(src + 3072);
            u16x4 l2 = *(const u16x4*)(src + 2*3072);
            u16x4 l3 = *(const u16x4*)(src + 3*3072);
            #pragma unroll
            for (int i = 0; i < 4; ++i) {
                u16x4 o; o[0] = l0[i]; o[1] = l1[i]; o[2] = l2[i]; o[3] = l3[i];
                int d = vd0 + i;
                *(u16x4*)((char*)Vt + ((d*128 + vs0*2) ^ ((d & 7) << 4))) = o;
            }
        }
        __syncthreads();
        f32x4 sacc[4] = {};
        #pragma unroll
        for (int sn = 0; sn < 4; ++sn) {
            int srow = sn*16 + lo;
            int rb = srow * 128, sw = (srow & 7) << 4;
            s16x8 kf0 = *(const s16x8*)((const char*)Ks + ((rb + hi*16) ^ sw));
            s16x8 kf1 = *(const s16x8*)((const char*)Ks + ((rb + 64 + hi*16) ^ sw));
            sacc[sn] = __builtin_amdgcn_mfma_f32_16x16x32_bf16(qf0, kf0, sacc[sn], 0, 0, 0);
            sacc[sn] = __builtin_amdgcn_mfma_f32_16x16x32_bf16(qf1, kf1, sacc[sn], 0, 0, 0);
        }
        #pragma unroll
        for (int sn = 0; sn < 4; ++sn) {
            int sl = sn*16 + lo;
            #pragma unroll
            for (int r = 0; r < 4; ++r) {
                float v = sacc[sn][r];
                if (st == tt && sl > wave*16 + hi*4 + r) v = 0.0f;
                int tq = hi*4 + r;
                *(ushort*)((char*)Ss[wave] + ((tq*128 + sl*2) ^ ((tq & 7) << 4))) = f2bf(v);
            }
        }
        s16x8 sa0 = *(const s16x8*)((const char*)Ss[wave] + ((lo*128 + hi*16) ^ ((lo & 7) << 4)));
        s16x8 sa1 = *(const s16x8*)((const char*)Ss[wave] + ((lo*128 + 64 + hi*16) ^ ((lo & 7) << 4)));
        #pragma unroll
        for (int dn = 0; dn < 4; ++dn) {
            int d = dn*16 + lo;
            int rb = d * 128, sw = (d & 7) << 4;
            s16x8 vf0 = *(const s16x8*)((const char*)Vt + ((rb + hi*16) ^ sw));
            s16x8 vf1 = *(const s16x8*)((const char*)Vt + ((rb + 64 + hi*16) ^ sw));
            accy[dn] = __builtin_amdgcn_mfma_f32_16x16x32_bf16(sa0, vf0, accy[dn], 0, 0, 0);
            accy[dn] = __builtin_amdgcn_mfma_f32_16x16x32_bf16(sa1, vf1, accy[dn], 0, 0, 0);
        }
    }
    #pragma unroll
    for (int dn = 0; dn < 4; ++dn) {
        #pragma unroll
        for (int r = 0; r < 4; ++r) {
            int t = t0 + wave*16 + hi*4 + r;
            y[(bT + t) * C_ + h*64 + dn*16 + lo] = accy[dn][r];
        }
    }
}

// ------- GroupNorm(per token, per head) * silu-gate -> bf16 ygated -------
__global__ __launch_bounds__(256) void gn_gate_kernel(const float* __restrict__ y,
                                                      const float* __restrict__ gate,
                                                      const float* __restrict__ gn_w,
                                                      const float* __restrict__ gn_b,
                                                      ushort* __restrict__ ygb) {
    int bt = blockIdx.x;
    int tid = threadIdx.x;
    float4 v = ((const float4*)(y + (size_t)bt * C_))[tid];
    float s1 = v.x + v.y + v.z + v.w;
    float s2 = v.x*v.x + v.y*v.y + v.z*v.z + v.w*v.w;
    #pragma unroll
    for (int m = 1; m < 16; m <<= 1) { s1 += __shfl_xor(s1, m); s2 += __shfl_xor(s2, m); }
    float mu   = s1 * (1.0f/64.0f);
    float var  = s2 * (1.0f/64.0f) - mu*mu;
    float rstd = rsqrtf(var + 1e-5f);
    float4 w  = ((const float4*)gn_w)[tid];
    float4 bb = ((const float4*)gn_b)[tid];
    float4 g  = ((const float4*)(gate + (size_t)bt * C_))[tid];
    u16x4 o;
    o[0] = f2bf(((v.x - mu)*rstd*w.x + bb.x) * g.x);
    o[1] = f2bf(((v.y - mu)*rstd*w.y + bb.y) * g.y);
    o[2] = f2bf(((v.z - mu)*rstd*w.z + bb.z) * g.z);
    o[3] = f2bf(((v.w - mu)*rstd*w.w + bb.w) * g.w);
    *(u16x4*)(ygb + (size_t)bt * C_ + 4*tid) = o;
}

extern "C" void kernel_launch(void* const* d_in, const int* in_sizes, int n_in,
                              void* d_out, int out_size, void* d_ws, size_t ws_size,
                              hipStream_t stream) {
    (void)in_sizes; (void)n_in; (void)out_size; (void)ws_size;
    const float* x       = (const float*)d_in[0];
    const float* w_qkvff = (const float*)d_in[1];
    const float* w_gated = (const float*)d_in[2];
    const float* b_gated = (const float*)d_in[3];
    const float* w_proj  = (const float*)d_in[4];
    const float* b_proj  = (const float*)d_in[5];
    const float* gn_w    = (const float*)d_in[6];
    const float* gn_b    = (const float*)d_in[7];
    const float* w_ff    = (const float*)d_in[8];
    const float* rms_w   = (const float*)d_in[9];
    float* out = (float*)d_out;

    const size_t NTOK = (size_t)B_ * T_;                  // 4096
    float* buf0  = (float*)d_ws;                          // ff_out
    float* buf1  = buf0 + NTOK * C_;                      // y (attention out)
    float* buf2  = buf1 + NTOK * C_;                      // gate (fp32)
    float* qkvff = buf2 + NTOK * C_;                      // 4096 x 5120 fp32
    ushort* qkvb = (ushort*)(qkvff + NTOK * FC_);         // 4096 x 3072 bf16
    ushort* xb   = qkvb + NTOK * 3072;                    // x bf16
    ushort* xnb  = xb + NTOK * C_;                        // rmsnorm(x) bf16
    ushort* ffb  = xnb + NTOK * C_;                       // gelu(ff) bf16 (4096x2048)
    ushort* ygb  = ffb + NTOK * 2048;                     // ygated bf16
    ushort* wqb  = ygb + NTOK * C_;                       // w_qkvff bf16 (5120x1024)
    ushort* wgb  = wqb + (size_t)FC_ * C_;                // w_gated bf16
    ushort* wpb  = wgb + (size_t)C_ * C_;                 // w_proj bf16
    ushort* wfb  = wpb + (size_t)C_ * C_;                 // w_ff bf16 (1024x2048)

    // weight / input bf16 conversions (independent)
    cvt_bf16_kernel<<<2048, 256, 0, stream>>>(x, xb, 524288);
    cvt_bf16_kernel<<<2560, 256, 0, stream>>>(w_qkvff, wqb, 655360);
    cvt_bf16_kernel<<<512,  256, 0, stream>>>(w_gated, wgb, 131072);
    cvt_bf16_kernel<<<512,  256, 0, stream>>>(w_proj,  wpb, 131072);
    cvt_bf16_kernel<<<1024, 256, 0, stream>>>(w_ff,    wfb, 262144);
    // RMSNorm -> bf16
    rmsnorm_kernel<<<4096, 256, 0, stream>>>(x, rms_w, xnb);
    // qkvff = xn @ w_qkvff^T  (M=4096, N=5120, K=1024) -> fp32
    gemm_bf16_kernel<0><<<dim3(40, 32), 256, 0, stream>>>(xnb, C_, wqb, C_, qkvff, FC_, C_,
                                                          nullptr, nullptr, nullptr);
    // xpos + decay prescale + pack q,k,v -> bf16
    xpos_bf16_kernel<<<4096, 256, 0, stream>>>(qkvff, qkvb);
    // gelu(ff) -> bf16
    gelu_bf16_kernel<<<4096, 256, 0, stream>>>(qkvff, ffb);
    // retention attention -> y (fp32)
    attn_mfma_kernel<<<dim3(32, 16, 2), 256, 0, stream>>>(qkvb, buf1);
    // gate = silu(x @ w_gated^T + b_gated) -> fp32
    gemm_bf16_kernel<1><<<dim3(8, 32), 256, 0, stream>>>(xb, C_, wgb, C_, buf2, C_, C_,
                                                         b_gated, nullptr, nullptr);
    // ygated = gate * (GN(y)*gn_w + gn_b) -> bf16
    gn_gate_kernel<<<4096, 256, 0, stream>>>(buf1, buf2, gn_w, gn_b, ygb);
    // ff_out = gelu(ff) @ w_ff^T  (K=2048) -> fp32
    gemm_bf16_kernel<0><<<dim3(8, 32), 256, 0, stream>>>(ffb, 2*C_, wfb, 2*C_, buf0, C_, 2*C_,
                                                         nullptr, nullptr, nullptr);
    // out = x + ff_out + (ygated @ w_proj^T + b_proj)
    gemm_bf16_kernel<2><<<dim3(8, 32), 256, 0, stream>>>(ygb, C_, wpb, C_, out, C_, C_,
                                                         b_proj, x, buf0);
}

// Round 6
// 324.373 us; speedup vs baseline: 6.4979x; 1.0766x over previous
//
#include <hip/hip_runtime.h>
#include <math.h>

#define B_  2
#define T_  2048
#define C_  1024
#define H_  16
#define FC_ 5120   // 5*C

typedef __attribute__((ext_vector_type(8))) short  s16x8;
typedef __attribute__((ext_vector_type(4))) float  f32x4;
typedef __attribute__((ext_vector_type(2))) unsigned short u16x2;
typedef __attribute__((ext_vector_type(4))) unsigned short u16x4;
typedef __attribute__((ext_vector_type(8))) unsigned short u16x8;

__device__ __forceinline__ ushort f2bf(float f) {
    union { float f; unsigned u; } v; v.f = f;
    unsigned r = v.u + 0x7FFFu + ((v.u >> 16) & 1u);   // round-to-nearest-even
    return (ushort)(r >> 16);
}
__device__ __forceinline__ float bf2f(ushort u) {
    union { unsigned u; float f; } v; v.u = (unsigned)u << 16; return v.f;
}

// ---------------- fp32 -> bf16 bulk convert (8 elems/thread) ----------------
__global__ __launch_bounds__(256) void cvt_bf16_kernel(const float* __restrict__ src,
                                                       ushort* __restrict__ dst, int n8) {
    int i = blockIdx.x * 256 + threadIdx.x;
    if (i >= n8) return;
    float4 a = ((const float4*)src)[2*i];
    float4 b = ((const float4*)src)[2*i + 1];
    u16x8 o;
    o[0] = f2bf(a.x); o[1] = f2bf(a.y); o[2] = f2bf(a.z); o[3] = f2bf(a.w);
    o[4] = f2bf(b.x); o[5] = f2bf(b.y); o[6] = f2bf(b.z); o[7] = f2bf(b.w);
    *(u16x8*)(dst + 8*i) = o;
}

// ---------------- RMSNorm -> bf16 ----------------
__global__ __launch_bounds__(256) void rmsnorm_kernel(const float* __restrict__ x,
                                                      const float* __restrict__ rms_w,
                                                      ushort* __restrict__ xn) {
    int row = blockIdx.x;
    int tid = threadIdx.x;
    float4 v = ((const float4*)(x + (size_t)row * C_))[tid];
    float ss = v.x*v.x + v.y*v.y + v.z*v.z + v.w*v.w;
    #pragma unroll
    for (int m = 32; m >= 1; m >>= 1) ss += __shfl_xor(ss, m);
    __shared__ float wsum[4];
    if ((tid & 63) == 0) wsum[tid >> 6] = ss;
    __syncthreads();
    float tot = wsum[0] + wsum[1] + wsum[2] + wsum[3];
    float nrm = sqrtf(tot) * 0.03125f;
    float inv = 1.0f / fmaxf(nrm, 1e-8f);
    float4 w = ((const float4*)rms_w)[tid];
    u16x4 o;
    o[0] = f2bf(v.x * inv * w.x);  o[1] = f2bf(v.y * inv * w.y);
    o[2] = f2bf(v.z * inv * w.z);  o[3] = f2bf(v.w * inv * w.w);
    *(u16x4*)(xn + (size_t)row * C_ + 4*tid) = o;
}

// ---- xpos rotary + decay pre-scale on bf16 q,k:  qkvb[q|k] = rot(qk)*scales ----
__global__ __launch_bounds__(256) void xpos_bf16_kernel(const ushort* __restrict__ qktmp,
                                                        ushort* __restrict__ qkv) {
    int bt = blockIdx.x;
    int t = bt & (T_ - 1);
    float tf = (float)t;
    const ushort* row = qktmp + (size_t)bt * 2048;
    ushort* orow = qkv + (size_t)bt * 3072;
    float power = (tf - 1024.0f) * (1.0f / 512.0f);
    for (int i = threadIdx.x; i < 512; i += 256) {       // pair index, half=512
        float sv    = (2.0f * (float)i + 409.6f) * (1.0f / 1433.6f);
        float scale = exp2f(power * log2f(sv));
        float invf  = exp2f((float)i * (-13.287712379549449f / 512.0f));
        float ang   = tf * invf;
        float sn, cs;
        sincosf(ang, &sn, &cs);
        float rs = 1.0f / scale;
        int hh = i >> 5;                                  // head of this pair
        float lg2g = log2f(1.0f - exp2f(-5.0f - (float)hh));
        float gq = exp2f(lg2g * tf) * 0.125f;             // 0.125 * gamma^t
        float gk = exp2f(-lg2g * tf);                     // gamma^-t
        u16x2 qi = *(const u16x2*)(row + 2*i);
        u16x2 ki = *(const u16x2*)(row + 1024 + 2*i);
        float qx = bf2f(qi[0]), qy = bf2f(qi[1]);
        float kx = bf2f(ki[0]), ky = bf2f(ki[1]);
        float qox = (qx*(cs*scale) - qy*(sn*scale)) * gq;
        float qoy = (qy*(cs*scale) + qx*(sn*scale)) * gq;
        float kox = (kx*(cs*rs) - ky*(sn*rs)) * gk;
        float koy = (ky*(cs*rs) + kx*(sn*rs)) * gk;
        u16x2 qo; qo[0] = f2bf(qox); qo[1] = f2bf(qoy);
        u16x2 ko; ko[0] = f2bf(kox); ko[1] = f2bf(koy);
        *(u16x2*)(orow + 2*i) = qo;
        *(u16x2*)(orow + 1024 + 2*i) = ko;
    }
}

// ---------------- bf16 MFMA GEMM: C = A(MxK) @ W(NxK)^T ----------------
// Tile 128 x BN (BN=128 or 64), BK=64, 4 waves. LDS XOR-swizzle byte^=(row&7)<<4.
// EPI: 0 plain fp32, 1 silu(acc+bias), 2 acc+bias+add1+add2,
//      3 qkvff routing: n<2048 -> oqk bf16; n<3072 -> ov (qkvb) bf16; else gelu -> offb bf16
template<int EPI, int BN>
__global__ __launch_bounds__(256) void gemm_bf16_kernel(
        const ushort* __restrict__ A, int lda,
        const ushort* __restrict__ W, int ldw,
        float* __restrict__ Cmat, int ldc, int K,
        const float* __restrict__ bias,
        const float* __restrict__ add1,
        const float* __restrict__ add2,
        ushort* __restrict__ oqk,
        ushort* __restrict__ ov,
        ushort* __restrict__ offb) {
    constexpr int NG = BN / 32;                 // n-frags per wave
    __shared__ __align__(16) ushort As[128*64];
    __shared__ __align__(16) ushort Bs[BN*64];
    int tid = threadIdx.x;
    int m0 = blockIdx.y * 128, n0 = blockIdx.x * BN;
    int wave = tid >> 6, lane = tid & 63;
    int lo = lane & 15, hi = lane >> 4;
    int wm = (wave >> 1) * 64, wn = (wave & 1) * (BN/2);
    int sra = tid >> 3, sua = tid & 7;          // A staging: 4 rows x 16B
    f32x4 acc[4][NG] = {};

    u16x8 ra[4], rb[4];
    auto loadA = [&](int k0) {
        #pragma unroll
        for (int i = 0; i < 4; ++i)
            ra[i] = *(const u16x8*)(A + (size_t)(m0 + sra + 32*i) * lda + k0 + sua*8);
    };
    auto loadB = [&](int k0) {
        if constexpr (BN == 128) {
            #pragma unroll
            for (int i = 0; i < 4; ++i)
                rb[i] = *(const u16x8*)(W + (size_t)(n0 + sra + 32*i) * ldw + k0 + sua*8);
        } else {
            int r = tid >> 2, c = tid & 3;
            rb[0] = *(const u16x8*)(W + (size_t)(n0 + r) * ldw + k0 + c*8);
            rb[1] = *(const u16x8*)(W + (size_t)(n0 + r) * ldw + k0 + (c+4)*8);
        }
    };
    loadA(0); loadB(0);
    for (int k0 = 0;;) {
        __syncthreads();
        #pragma unroll
        for (int i = 0; i < 4; ++i) {
            int row = sra + 32*i;
            *(u16x8*)((char*)As + (row*128 + ((sua*16) ^ ((row & 7) << 4)))) = ra[i];
        }
        if constexpr (BN == 128) {
            #pragma unroll
            for (int i = 0; i < 4; ++i) {
                int row = sra + 32*i;
                *(u16x8*)((char*)Bs + (row*128 + ((sua*16) ^ ((row & 7) << 4)))) = rb[i];
            }
        } else {
            int r = tid >> 2, c = tid & 3, sw = (r & 7) << 4;
            *(u16x8*)((char*)Bs + (r*128 + ((c*16) ^ sw)))     = rb[0];
            *(u16x8*)((char*)Bs + (r*128 + (((c+4)*16) ^ sw))) = rb[1];
        }
        __syncthreads();
        k0 += 64;
        if (k0 < K) { loadA(k0); loadB(k0); }
        #pragma unroll
        for (int kc = 0; kc < 2; ++kc) {
            s16x8 af[4], bf[NG];
            #pragma unroll
            for (int g = 0; g < 4; ++g) {
                int arow = wm + g*16 + lo;
                af[g] = *(const s16x8*)((const char*)As +
                         arow*128 + ((kc*64 + hi*16) ^ ((arow & 7) << 4)));
            }
            #pragma unroll
            for (int g = 0; g < NG; ++g) {
                int brow = wn + g*16 + lo;
                bf[g] = *(const s16x8*)((const char*)Bs +
                         brow*128 + ((kc*64 + hi*16) ^ ((brow & 7) << 4)));
            }
            #pragma unroll
            for (int mg = 0; mg < 4; ++mg)
                #pragma unroll
                for (int ng = 0; ng < NG; ++ng)
                    acc[mg][ng] = __builtin_amdgcn_mfma_f32_16x16x32_bf16(
                        af[mg], bf[ng], acc[mg][ng], 0, 0, 0);
        }
        if (k0 >= K) break;
    }
    #pragma unroll
    for (int mg = 0; mg < 4; ++mg) {
        #pragma unroll
        for (int r = 0; r < 4; ++r) {
            size_t m = (size_t)(m0 + wm + mg*16 + hi*4 + r);
            #pragma unroll
            for (int ng = 0; ng < NG; ++ng) {
                int n = n0 + wn + ng*16 + lo;
                float v = acc[mg][ng][r];
                if constexpr (EPI == 3) {
                    if (n0 < 2048)      oqk[m*2048 + n] = f2bf(v);
                    else if (n0 < 3072) ov[m*3072 + n] = f2bf(v);
                    else offb[m*2048 + (n - 3072)] =
                             f2bf(0.5f * v * (1.0f + erff(v * 0.70710678118f)));
                } else {
                    if (EPI == 1) {
                        float s = v + bias[n];
                        v = s / (1.0f + expf(-s));
                    } else if (EPI == 2) {
                        v += bias[n] + add1[m*ldc + n] + add2[m*ldc + n];
                    }
                    Cmat[m*ldc + n] = v;
                }
            }
        }
    }
}

// ---------------- retention attention, paired q-tiles (tt, 31-tt) ----------------
// Per block: q-tiles tta=pair, ttb=31-pair share K/V staging; constant 33 compute units.
// Double-buffered LDS, one barrier per s-tile, reg-prefetch of next tile.
__global__ __launch_bounds__(256) void attn_mfma2_kernel(const ushort* __restrict__ qkv,
                                                         float* __restrict__ y) {
    __shared__ ushort Ks[2][64*64];
    __shared__ ushort Vt[2][64*64];
    __shared__ ushort Ss[4][16*64];
    int F = blockIdx.x;                     // 0..511
    int o = (F & 7) * 64 + (F >> 3);        // XCD grouping: o/64 == XCD (round-robin)
    int tta = o & 15;
    int h   = (o >> 4) & 15;
    int b   = o >> 8;
    int ttb = 31 - tta;
    int t0a = tta * 64, t0b = ttb * 64;
    int tid = threadIdx.x;
    int wave = tid >> 6, lane = tid & 63;
    int lo = lane & 15, hi = lane >> 4;
    const size_t bT = (size_t)b * T_;

    const ushort* qra = qkv + (bT + t0a + wave*16 + lo) * 3072 + h*64;
    const ushort* qrb = qkv + (bT + t0b + wave*16 + lo) * 3072 + h*64;
    s16x8 qa0 = *(const s16x8*)(qra + hi*8);
    s16x8 qa1 = *(const s16x8*)(qra + 32 + hi*8);
    s16x8 qb0 = *(const s16x8*)(qrb + hi*8);
    s16x8 qb1 = *(const s16x8*)(qrb + 32 + hi*8);
    f32x4 acca[4] = {}, accb[4] = {};

    int kr = tid >> 2, kc = tid & 3;                 // K staging
    int vd0 = (tid & 15) * 4, vs0 = (tid >> 4) * 4;  // V staging transpose
    u16x8 rka, rkb;
    u16x4 rv0, rv1, rv2, rv3;
    auto loadt = [&](int s0) {
        const ushort* src = qkv + (bT + s0 + kr) * 3072 + 1024 + h*64;
        rka = *(const u16x8*)(src + kc*8);
        rkb = *(const u16x8*)(src + (kc+4)*8);
        const ushort* vsrc = qkv + (bT + s0 + vs0) * 3072 + 2048 + h*64 + vd0;
        rv0 = *(const u16x4*)(vsrc);
        rv1 = *(const u16x4*)(vsrc + 3072);
        rv2 = *(const u16x4*)(vsrc + 2*3072);
        rv3 = *(const u16x4*)(vsrc + 3*3072);
    };
    int cur = 0;
    loadt(0);
    for (int st = 0; st <= ttb; ++st) {
        {   // write staged regs into LDS[cur]
            int base = kr * 128, sw = (kr & 7) << 4;
            *(u16x8*)((char*)Ks[cur] + ((base + kc*16) ^ sw))     = rka;
            *(u16x8*)((char*)Ks[cur] + ((base + (kc+4)*16) ^ sw)) = rkb;
            #pragma unroll
            for (int i = 0; i < 4; ++i) {
                u16x4 o4; o4[0] = rv0[i]; o4[1] = rv1[i]; o4[2] = rv2[i]; o4[3] = rv3[i];
                int d = vd0 + i;
                *(u16x4*)((char*)Vt[cur] + ((d*128 + vs0*2) ^ ((d & 7) << 4))) = o4;
            }
        }
        __syncthreads();
        if (st < ttb) loadt((st + 1) * 64);   // prefetch overlaps compute below

        auto compute = [&](s16x8 q0, s16x8 q1, f32x4* accy, bool diag) {
            f32x4 sacc[4] = {};
            #pragma unroll
            for (int sn = 0; sn < 4; ++sn) {
                int srow = sn*16 + lo;
                int rb2 = srow * 128, sw = (srow & 7) << 4;
                s16x8 kf0 = *(const s16x8*)((const char*)Ks[cur] + ((rb2 + hi*16) ^ sw));
                s16x8 kf1 = *(const s16x8*)((const char*)Ks[cur] + ((rb2 + 64 + hi*16) ^ sw));
                sacc[sn] = __builtin_amdgcn_mfma_f32_16x16x32_bf16(q0, kf0, sacc[sn], 0, 0, 0);
                sacc[sn] = __builtin_amdgcn_mfma_f32_16x16x32_bf16(q1, kf1, sacc[sn], 0, 0, 0);
            }
            #pragma unroll
            for (int sn = 0; sn < 4; ++sn) {
                int sl = sn*16 + lo;
                #pragma unroll
                for (int r = 0; r < 4; ++r) {
                    float v = sacc[sn][r];
                    if (diag && sl > wave*16 + hi*4 + r) v = 0.0f;
                    int tq = hi*4 + r;
                    *(ushort*)((char*)Ss[wave] + ((tq*128 + sl*2) ^ ((tq & 7) << 4))) = f2bf(v);
                }
            }
            s16x8 sa0 = *(const s16x8*)((const char*)Ss[wave] + ((lo*128 + hi*16) ^ ((lo & 7) << 4)));
            s16x8 sa1 = *(const s16x8*)((const char*)Ss[wave] + ((lo*128 + 64 + hi*16) ^ ((lo & 7) << 4)));
            #pragma unroll
            for (int dn = 0; dn < 4; ++dn) {
                int d = dn*16 + lo;
                int rb2 = d * 128, sw = (d & 7) << 4;
                s16x8 vf0 = *(const s16x8*)((const char*)Vt[cur] + ((rb2 + hi*16) ^ sw));
                s16x8 vf1 = *(const s16x8*)((const char*)Vt[cur] + ((rb2 + 64 + hi*16) ^ sw));
                accy[dn] = __builtin_amdgcn_mfma_f32_16x16x32_bf16(sa0, vf0, accy[dn], 0, 0, 0);
                accy[dn] = __builtin_amdgcn_mfma_f32_16x16x32_bf16(sa1, vf1, accy[dn], 0, 0, 0);
            }
        };
        compute(qb0, qb1, accb, st == ttb);          // B-tile: always active
        if (st <= tta) compute(qa0, qa1, acca, st == tta);
        cur ^= 1;
    }
    #pragma unroll
    for (int dn = 0; dn < 4; ++dn) {
        #pragma unroll
        for (int r = 0; r < 4; ++r) {
            int ta = t0a + wave*16 + hi*4 + r;
            int tb = t0b + wave*16 + hi*4 + r;
            y[(bT + ta) * C_ + h*64 + dn*16 + lo] = acca[dn][r];
            y[(bT + tb) * C_ + h*64 + dn*16 + lo] = accb[dn][r];
        }
    }
}

// ------- GroupNorm(per token, per head) * silu-gate -> bf16 ygated -------
__global__ __launch_bounds__(256) void gn_gate_kernel(const float* __restrict__ y,
                                                      const float* __restrict__ gate,
                                                      const float* __restrict__ gn_w,
                                                      const float* __restrict__ gn_b,
                                                      ushort* __restrict__ ygb) {
    int bt = blockIdx.x;
    int tid = threadIdx.x;
    float4 v = ((const float4*)(y + (size_t)bt * C_))[tid];
    float s1 = v.x + v.y + v.z + v.w;
    float s2 = v.x*v.x + v.y*v.y + v.z*v.z + v.w*v.w;
    #pragma unroll
    for (int m = 1; m < 16; m <<= 1) { s1 += __shfl_xor(s1, m); s2 += __shfl_xor(s2, m); }
    float mu   = s1 * (1.0f/64.0f);
    float var  = s2 * (1.0f/64.0f) - mu*mu;
    float rstd = rsqrtf(var + 1e-5f);
    float4 w  = ((const float4*)gn_w)[tid];
    float4 bb = ((const float4*)gn_b)[tid];
    float4 g  = ((const float4*)(gate + (size_t)bt * C_))[tid];
    u16x4 o;
    o[0] = f2bf(((v.x - mu)*rstd*w.x + bb.x) * g.x);
    o[1] = f2bf(((v.y - mu)*rstd*w.y + bb.y) * g.y);
    o[2] = f2bf(((v.z - mu)*rstd*w.z + bb.z) * g.z);
    o[3] = f2bf(((v.w - mu)*rstd*w.w + bb.w) * g.w);
    *(u16x4*)(ygb + (size_t)bt * C_ + 4*tid) = o;
}

extern "C" void kernel_launch(void* const* d_in, const int* in_sizes, int n_in,
                              void* d_out, int out_size, void* d_ws, size_t ws_size,
                              hipStream_t stream) {
    (void)in_sizes; (void)n_in; (void)out_size; (void)ws_size;
    const float* x       = (const float*)d_in[0];
    const float* w_qkvff = (const float*)d_in[1];
    const float* w_gated = (const float*)d_in[2];
    const float* b_gated = (const float*)d_in[3];
    const float* w_proj  = (const float*)d_in[4];
    const float* b_proj  = (const float*)d_in[5];
    const float* gn_w    = (const float*)d_in[6];
    const float* gn_b    = (const float*)d_in[7];
    const float* w_ff    = (const float*)d_in[8];
    const float* rms_w   = (const float*)d_in[9];
    float* out = (float*)d_out;

    const size_t NTOK = (size_t)B_ * T_;                  // 4096
    float* buf0   = (float*)d_ws;                         // ff_out fp32
    float* buf1   = buf0 + NTOK * C_;                     // y fp32
    float* buf2   = buf1 + NTOK * C_;                     // gate fp32
    ushort* qkvb  = (ushort*)(buf2 + NTOK * C_);          // 4096 x 3072 bf16 (q|k|v)
    ushort* qktmp = qkvb + NTOK * 3072;                   // 4096 x 2048 bf16 (pre-xpos q,k)
    ushort* xb    = qktmp + NTOK * 2048;                  // x bf16
    ushort* xnb   = xb + NTOK * C_;                       // rmsnorm(x) bf16
    ushort* ffb   = xnb + NTOK * C_;                      // gelu(ff) bf16 (4096x2048)
    ushort* ygb   = ffb + NTOK * 2048;                    // ygated bf16
    ushort* wqb   = ygb + NTOK * C_;                      // w_qkvff bf16 (5120x1024)
    ushort* wgb   = wqb + (size_t)FC_ * C_;               // w_gated bf16
    ushort* wpb   = wgb + (size_t)C_ * C_;                // w_proj bf16
    ushort* wfb   = wpb + (size_t)C_ * C_;                // w_ff bf16 (1024x2048)

    cvt_bf16_kernel<<<2048, 256, 0, stream>>>(x, xb, 524288);
    cvt_bf16_kernel<<<2560, 256, 0, stream>>>(w_qkvff, wqb, 655360);
    cvt_bf16_kernel<<<512,  256, 0, stream>>>(w_gated, wgb, 131072);
    cvt_bf16_kernel<<<512,  256, 0, stream>>>(w_proj,  wpb, 131072);
    cvt_bf16_kernel<<<1024, 256, 0, stream>>>(w_ff,    wfb, 262144);
    rmsnorm_kernel<<<4096, 256, 0, stream>>>(x, rms_w, xnb);
    // qkvff GEMM with routed bf16 epilogue: q,k -> qktmp; v -> qkvb; gelu(ff) -> ffb
    gemm_bf16_kernel<3,128><<<dim3(40, 32), 256, 0, stream>>>(
        xnb, C_, wqb, C_, nullptr, 0, C_, nullptr, nullptr, nullptr, qktmp, qkvb, ffb);
    // xpos + decay prescale on q,k
    xpos_bf16_kernel<<<4096, 256, 0, stream>>>(qktmp, qkvb);
    // retention attention (paired tiles) -> y fp32
    attn_mfma2_kernel<<<512, 256, 0, stream>>>(qkvb, buf1);
    // gate = silu(x @ w_gated^T + b_gated) -> fp32
    gemm_bf16_kernel<1,64><<<dim3(16, 32), 256, 0, stream>>>(
        xb, C_, wgb, C_, buf2, C_, C_, b_gated, nullptr, nullptr, nullptr, nullptr, nullptr);
    // ygated = gate * (GN(y)*gn_w + gn_b) -> bf16
    gn_gate_kernel<<<4096, 256, 0, stream>>>(buf1, buf2, gn_w, gn_b, ygb);
    // ff_out = gelu(ff) @ w_ff^T  (K=2048) -> fp32
    gemm_bf16_kernel<0,64><<<dim3(16, 32), 256, 0, stream>>>(
        ffb, 2*C_, wfb, 2*C_, buf0, C_, 2*C_, nullptr, nullptr, nullptr, nullptr, nullptr, nullptr);
    // out = x + ff_out + (ygated @ w_proj^T + b_proj)
    gemm_bf16_kernel<2,64><<<dim3(16, 32), 256, 0, stream>>>(
        ygb, C_, wpb, C_, out, C_, C_, b_proj, x, buf0, nullptr, nullptr, nullptr);
}